// Round 16
// baseline (223.505 us; speedup 1.0000x reference)
//
#include <hip/hip_runtime.h>
#include <hip/hip_bf16.h>

typedef unsigned short u16;
typedef __attribute__((ext_vector_type(8))) short short8;   // 8 bf16
typedef __attribute__((ext_vector_type(4))) short bf16x4;   // 4 bf16
typedef __attribute__((ext_vector_type(4))) float f32x4;
typedef __attribute__((ext_vector_type(4))) int i32x4;
typedef __attribute__((ext_vector_type(2))) unsigned u32x2;

#define DEV __device__ __forceinline__

DEV float bf2f(u16 v){ unsigned u = ((unsigned)v)<<16; float f; __builtin_memcpy(&f,&u,4); return f; }
DEV u16 f2bf(float f){ unsigned u; __builtin_memcpy(&u,&f,4); u += 0x7fff + ((u>>16)&1); return (u16)(u>>16); }

// async 16B global -> LDS (wave-uniform LDS base + lane*16; per-lane global addr)
DEV void gload16(const void* g, void* l){
  __builtin_amdgcn_global_load_lds((const __attribute__((address_space(1))) void*)g,
                                   (__attribute__((address_space(3))) void*)l, 16, 0, 0);
}

// pack two f32 -> one u32 of 2 bf16 via compiler-managed cvt_pk
DEV unsigned packbf2(float a, float b){
  float2 f = {a, b};
  __hip_bfloat162 h = __float22bfloat162_rn(f);
  unsigned w; __builtin_memcpy(&w, &h, 4);
  return w;
}

// dims: B=4 S=2048 D=512 H=8 HD=64 E=8 K=2 F=1024, T=8192

// ---------------- coalesced transpose+convert: src fp32 [R][C] -> dst bf16 [C][R], z selects matrix ----------------
__global__ __launch_bounds__(256) void k_tconv4(const float* __restrict__ s0, const float* __restrict__ s1,
    const float* __restrict__ s2, const float* __restrict__ s3, u16* __restrict__ dst){
  int z = blockIdx.z;
  const float* src = z==0 ? s0 : (z==1 ? s1 : (z==2 ? s2 : s3));
  dst += (size_t)z * 512 * 512;
  int r0 = blockIdx.y * 64, c0 = blockIdx.x * 64;
  __shared__ u16 tile[64][68];
  int tid = threadIdx.x;
  int rr = tid >> 4, cc = (tid & 15) * 4;
  #pragma unroll
  for (int it = 0; it < 4; ++it){
    int r = it*16 + rr;
    float4 v = *(const float4*)(src + (size_t)(r0 + r)*512 + c0 + cc);
    bf16x4 pk = { (short)f2bf(v.x), (short)f2bf(v.y), (short)f2bf(v.z), (short)f2bf(v.w) };
    *(bf16x4*)&tile[r][cc] = pk;
  }
  __syncthreads();
  #pragma unroll
  for (int it = 0; it < 4; ++it){
    int c = it*16 + rr;
    bf16x4 pk = { (short)tile[cc+0][c], (short)tile[cc+1][c],
                  (short)tile[cc+2][c], (short)tile[cc+3][c] };
    *(bf16x4*)(dst + (size_t)(c0 + c)*512 + r0 + cc) = pk;
  }
}

__global__ __launch_bounds__(256) void k_tconv(const float* __restrict__ src, u16* __restrict__ dst,
    int R, int C){
  src += (size_t)blockIdx.z * R * C;
  dst += (size_t)blockIdx.z * R * C;
  int r0 = blockIdx.y * 64, c0 = blockIdx.x * 64;
  __shared__ u16 tile[64][68];
  int tid = threadIdx.x;
  int rr = tid >> 4, cc = (tid & 15) * 4;
  #pragma unroll
  for (int it = 0; it < 4; ++it){
    int r = it*16 + rr;
    float4 v = *(const float4*)(src + (size_t)(r0 + r)*C + c0 + cc);
    bf16x4 pk = { (short)f2bf(v.x), (short)f2bf(v.y), (short)f2bf(v.z), (short)f2bf(v.w) };
    *(bf16x4*)&tile[r][cc] = pk;
  }
  __syncthreads();
  #pragma unroll
  for (int it = 0; it < 4; ++it){
    int c = it*16 + rr;
    bf16x4 pk = { (short)tile[cc+0][c], (short)tile[cc+1][c],
                  (short)tile[cc+2][c], (short)tile[cc+3][c] };
    *(bf16x4*)(dst + (size_t)(c0 + c)*R + r0 + cc) = pk;
  }
}

// ---------------- bf16 transpose per head: [2048 s][64 d] -> [64 d][2048 s] ----------------
__global__ __launch_bounds__(256) void k_vtrans(const u16* __restrict__ src, u16* __restrict__ dst){
  int bh = blockIdx.y; int s0 = blockIdx.x*64;
  src += (size_t)bh*2048*64 + (size_t)s0*64;
  dst += (size_t)bh*64*2048 + s0;
  __shared__ unsigned tile[64*33];
  int tid = threadIdx.x;
  #pragma unroll
  for (int it = 0; it < 2; ++it){
    int c = tid + it*256;
    int r = c >> 3, c8 = c & 7;
    i32x4 v = *(const i32x4*)(src + (size_t)r*64 + c8*8);
    *(i32x4*)&tile[r*33 + c8*4] = v;
  }
  __syncthreads();
  #pragma unroll
  for (int it = 0; it < 2; ++it){
    int c = tid + it*256;
    int d = c >> 3, s8 = c & 7;
    union { i32x4 v; u16 us[8]; } o;
    #pragma unroll
    for (int j = 0; j < 8; ++j){
      unsigned w = tile[(s8*8+j)*33 + (d>>1)];
      o.us[j] = (d & 1) ? (u16)(w >> 16) : (u16)(w & 0xffff);
    }
    *(i32x4*)(dst + (size_t)d*2048 + s8*8) = o.v;
  }
}

// ---------------- RMSNorm1 ----------------
__global__ __launch_bounds__(256) void k_rmsnorm(const float* __restrict__ x, const float* __restrict__ w,
    u16* __restrict__ ob){
  int t = blockIdx.x, tid = threadIdx.x;
  const float* xr = x + (size_t)t*512;
  float2 v = *(const float2*)(xr + tid*2);
  float ss = v.x*v.x + v.y*v.y;
  #pragma unroll
  for (int o=32; o>0; o>>=1) ss += __shfl_down(ss, o);
  __shared__ float sred[4];
  if ((tid&63)==0) sred[tid>>6] = ss;
  __syncthreads();
  float tot = sred[0]+sred[1]+sred[2]+sred[3];
  float inv = rsqrtf(tot*(1.f/512.f) + 1e-6f);
  float2 wv = *(const float2*)(w + tid*2);
  ob[(size_t)t*512 + tid*2]     = f2bf(v.x*inv*wv.x);
  ob[(size_t)t*512 + tid*2 + 1] = f2bf(v.y*inv*wv.y);
}

// ---------------- fused RMSNorm2 + gate logits + top-2 (fp32 X1 — routing must match fp32 reference) ----------------
__global__ __launch_bounds__(256) void k_rmsgate(const float* __restrict__ x, const float* __restrict__ w,
    const float* __restrict__ gw, u16* __restrict__ ob, int* __restrict__ topi, float* __restrict__ topw){
  int t = blockIdx.x, tid = threadIdx.x;
  const float* xr = x + (size_t)t*512;
  float2 v = *(const float2*)(xr + tid*2);
  float ss = v.x*v.x + v.y*v.y;
  #pragma unroll
  for (int o=32; o>0; o>>=1) ss += __shfl_down(ss, o);
  __shared__ float sred[4];
  if ((tid&63)==0) sred[tid>>6] = ss;
  __syncthreads();
  float tot = sred[0]+sred[1]+sred[2]+sred[3];
  float inv = rsqrtf(tot*(1.f/512.f) + 1e-6f);
  float2 wv = *(const float2*)(w + tid*2);
  float y0 = v.x*inv*wv.x, y1 = v.y*inv*wv.y;
  ob[(size_t)t*512 + tid*2]     = f2bf(y0);
  ob[(size_t)t*512 + tid*2 + 1] = f2bf(y1);
  float acc[8];
  const float* g0 = gw + tid*16;
  #pragma unroll
  for (int e=0;e<8;e++) acc[e] = y0*g0[e] + y1*g0[8+e];
  #pragma unroll
  for (int dd=1; dd<64; dd<<=1)
    #pragma unroll
    for (int e=0;e<8;e++) acc[e] += __shfl_xor(acc[e], dd);
  __shared__ float gred[4][8];
  if ((tid&63)==0)
    #pragma unroll
    for (int e=0;e<8;e++) gred[tid>>6][e] = acc[e];
  __syncthreads();
  if (tid==0){
    float l[8];
    #pragma unroll
    for (int e=0;e<8;e++) l[e] = gred[0][e]+gred[1][e]+gred[2][e]+gred[3][e];
    int i0=0; float a0=l[0];
    #pragma unroll
    for (int e=1;e<8;e++) if (l[e]>a0){ a0=l[e]; i0=e; }
    int i1=-1; float a1=-1e30f;
    #pragma unroll
    for (int e=0;e<8;e++) if (e!=i0 && l[e]>a1){ a1=l[e]; i1=e; }
    float w1 = __expf(a1 - a0);
    float invs = 1.f / (1.f + w1);
    topi[t*2]=i0; topi[t*2+1]=i1;
    topw[t*2]=invs; topw[t*2+1]=w1*invs;
  }
}

// ---------------- expert histogram ----------------
__global__ __launch_bounds__(256) void k_count(const int* __restrict__ topi, int* __restrict__ counts){
  __shared__ int lcnt[8];
  if (threadIdx.x < 8) lcnt[threadIdx.x] = 0;
  __syncthreads();
  for (int i = blockIdx.x*256 + threadIdx.x; i < 16384; i += 256*64)
    atomicAdd(&lcnt[topi[i]], 1);
  __syncthreads();
  if (threadIdx.x < 8) atomicAdd(&counts[threadIdx.x], lcnt[threadIdx.x]);
}

// ---------------- TN bf16 GEMM, global_load_lds + double-buffered; XCD-pinned experts ----------------
template<int MODE>
__global__ __launch_bounds__(256) void k_gemm(const u16* __restrict__ A, const u16* __restrict__ Bt,
    int Nsize, int Ksize,
    const float* __restrict__ b0, const float* __restrict__ b1, const float* __restrict__ b2,
    const float* __restrict__ resid, float* __restrict__ outf,
    u16* __restrict__ o0, u16* __restrict__ o1, u16* __restrict__ o2,
    const int* __restrict__ ebase, const int* __restrict__ ecnt, const int* __restrict__ etok)
{
  int nNT = Nsize >> 7;
  int e=0, mt, nt, myBase=0, myCnt=0;
  if constexpr (MODE>=2){
    e = blockIdx.x & 7;
    int rr = blockIdx.x >> 3;
    mt = rr / nNT; nt = rr - mt*nNT;
    myCnt = ecnt[e]; myBase = ebase[e];
    if (mt*128 >= myCnt) return;
    Bt += (size_t)e * Nsize * Ksize;
  } else {
    int q = gridDim.x >> 3;
    int bid = blockIdx.x;
    int swb = (bid & 7)*q + (bid >> 3);
    mt = swb / nNT; nt = swb - mt*nNT;
  }
  __shared__ u16 As[2][128*32];
  __shared__ u16 Bs[2][128*32];
  int tid = threadIdx.x;
  int lane = tid & 63, wid = tid >> 6;
  int wr = (wid>>1)<<6, wc = (wid&1)<<6;
  int lrow = lane & 15, lk8 = (lane>>4)<<3;
  const u16* asrc[2]; const u16* bsrc[2];
  int ldoff[2];
  #pragma unroll
  for (int it=0; it<2; ++it){
    int c = it*256 + tid;
    int r = c >> 2, c4 = c & 3;
    int grow;
    if constexpr (MODE==2){
      int ml = mt*128 + r; if (ml >= myCnt) ml = myCnt-1;
      grow = etok[myBase + ml];
    } else if constexpr (MODE==3){
      int ml = mt*128 + r; if (ml >= myCnt) ml = myCnt-1;
      grow = myBase + ml;
    } else {
      grow = mt*128 + r;
    }
    asrc[it] = A + (size_t)grow*Ksize + c4*8;
    bsrc[it] = Bt + (size_t)(nt*128 + r)*Ksize + c4*8;
    ldoff[it] = (it*256 + wid*64)*8;
  }
  f32x4 acc[4][4] = {};
  int nK = Ksize >> 5;
  #pragma unroll
  for (int it=0; it<2; ++it){
    gload16(asrc[it], &As[0][ldoff[it]]);
    gload16(bsrc[it], &Bs[0][ldoff[it]]);
  }
  __syncthreads();
  for (int ks = 0; ks < nK; ++ks){
    int cur = ks & 1;
    if (ks+1 < nK){
      int k0 = (ks+1) << 5;
      #pragma unroll
      for (int it=0; it<2; ++it){
        gload16(asrc[it] + k0, &As[cur^1][ldoff[it]]);
        gload16(bsrc[it] + k0, &Bs[cur^1][ldoff[it]]);
      }
    }
    short8 a[4], b[4];
    #pragma unroll
    for (int i=0;i<4;i++) a[i] = *(const short8*)(&As[cur][(wr + i*16 + lrow)*32 + lk8]);
    #pragma unroll
    for (int j=0;j<4;j++) b[j] = *(const short8*)(&Bs[cur][(wc + j*16 + lrow)*32 + lk8]);
    #pragma unroll
    for (int i=0;i<4;i++)
      #pragma unroll
      for (int j=0;j<4;j++)
        acc[i][j] = __builtin_amdgcn_mfma_f32_16x16x32_bf16(a[i], b[j], acc[i][j], 0,0,0);
    __syncthreads();
  }
  #pragma unroll
  for (int i=0;i<4;i++){
    #pragma unroll
    for (int r=0;r<4;r++){
      int rowl = mt*128 + wr + i*16 + ((lane>>4)<<2) + r;
      #pragma unroll
      for (int j=0;j<4;j++){
        int col = nt*128 + wc + j*16 + lrow;
        float v = acc[i][j][r];
        if constexpr (MODE==0){
          int which = col >> 9; int hc = col & 511;
          const float* bias = which==0 ? b0 : (which==1 ? b1 : b2);
          v += bias[hc];
          if (which == 0) v *= 0.18033688011112042f;   // fold 0.125*log2(e) into Q
          u16* dst = which==0 ? o0 : (which==1 ? o1 : o2);
          int bidx = rowl >> 11, s = rowl & 2047;
          int h = hc >> 6, hd = hc & 63;
          dst[((size_t)(bidx*8+h)*2048 + s)*64 + hd] = f2bf(v);
        } else if constexpr (MODE==1){
          v += b0[col] + resid[(size_t)rowl*512 + col];
          outf[(size_t)rowl*512 + col] = v;          // X1 fp32 (routing correctness)
        } else if constexpr (MODE==2){
          if (rowl < myCnt){
            v += b0[e*1024 + col];
            v = fmaxf(v, 0.f);
            o0[(size_t)(myBase+rowl)*1024 + col] = f2bf(v);
          }
        } else {
          if (rowl < myCnt){
            v += b0[e*512 + col];
            o0[(size_t)(myBase+rowl)*512 + col] = f2bf(v);
          }
        }
      }
    }
  }
}

// ---------------- flash attention v7: 16 waves x 16 q-rows (QBLK=256, KVBLK=128, 1024 thr, 64KB LDS) ----
__global__ __launch_bounds__(1024) void k_attn(const u16* __restrict__ qb, const u16* __restrict__ kb,
    const u16* __restrict__ vtb, u16* __restrict__ ctx)
{
  int bh = blockIdx.x & 31;        // XCD = bh % 8
  int qt = blockIdx.x >> 5;        // 8 q-tiles of 256
  int b = bh >> 3, h = bh & 7;
  const size_t bho = (size_t)bh * (2048*64);
  int tid = threadIdx.x, lane = tid & 63, wid = tid >> 6;   // 16 waves
  int lrow = lane & 15, g = lane >> 4;
  __shared__ u16 Ks[128*64];       // 16KB [key][d] rows 128B, XOR-swizzled
  __shared__ u16 Vts[64*128];      // 16KB [d][key] rows 256B, XOR-swizzled
  __shared__ u16 Ps[16][16*64];    // 32KB per-wave P [q][key-half] rows 128B, XOR-swizzled
  char* Ksb = (char*)Ks;
  char* Vsb = (char*)Vts;
  char* Psb = (char*)&Ps[wid][0];
  int q0 = qt*256 + wid*16;
  short8 qf[2];
  #pragma unroll
  for (int kf=0;kf<2;kf++)
    qf[kf] = *(const short8*)(qb + bho + (size_t)(q0 + lrow)*64 + kf*32 + g*8);
  f32x4 oacc[4] = {};
  float lpart = 0.f;
  const int swz = (lrow & 7) << 4;

  int c = tid;
  int kr = c >> 3, kc8 = c & 7;
  size_t ksrc = bho + (size_t)kr*64 + kc8*8;
  int kdst = kr*128 + ((kc8*16) ^ ((kr&7)<<4));
  int vr = c >> 4, vc16 = c & 15;
  size_t vsrc = bho + (size_t)vr*2048 + vc16*8;
  int vdst = vr*256 + ((vc16*16) ^ ((vr&7)<<4));

  i32x4 kreg = *(const i32x4*)(kb + ksrc);
  i32x4 vreg = *(const i32x4*)(vtb + vsrc);
  *(i32x4*)(Ksb + kdst) = kreg;
  *(i32x4*)(Vsb + vdst) = vreg;
  __syncthreads();

  for (int kt=0; kt<16; ++kt){
    if (kt < 15){
      int k0 = (kt+1)*128;
      kreg = *(const i32x4*)(kb + ksrc + (size_t)k0*64);
      vreg = *(const i32x4*)(vtb + vsrc + k0);
    }
    __builtin_amdgcn_s_setprio(1);
    #pragma unroll
    for (int hf=0; hf<2; ++hf){
      #pragma unroll
      for (int nf=0; nf<4; ++nf){
        int krow = hf*64 + nf*16 + lrow;
        short8 kf0 = *(const short8*)(Ksb + krow*128 + ((g*16) ^ swz));
        short8 kf1 = *(const short8*)(Ksb + krow*128 + ((64 + g*16) ^ swz));
        f32x4 s = {};
        s = __builtin_amdgcn_mfma_f32_16x16x32_bf16(kf0, qf[0], s, 0,0,0);
        s = __builtin_amdgcn_mfma_f32_16x16x32_bf16(kf1, qf[1], s, 0,0,0);
        float p0 = __builtin_amdgcn_exp2f(s[0]);
        float p1 = __builtin_amdgcn_exp2f(s[1]);
        float p2 = __builtin_amdgcn_exp2f(s[2]);
        float p3 = __builtin_amdgcn_exp2f(s[3]);
        lpart += (p0+p1)+(p2+p3);
        *(u32x2*)(Psb + lrow*128 + ((nf*32 + g*8) ^ swz)) = (u32x2){packbf2(p0,p1), packbf2(p2,p3)};
      }
      short8 pfr[2];
      #pragma unroll
      for (int kf=0;kf<2;kf++)
        pfr[kf] = *(const short8*)(Psb + lrow*128 + ((kf*64 + g*16) ^ swz));
      #pragma unroll
      for (int dn=0;dn<4;dn++){
        #pragma unroll
        for (int kf=0;kf<2;kf++){
          short8 vf = *(const short8*)(Vsb + (dn*16+lrow)*256 + ((hf*128 + kf*64 + g*16) ^ swz));
          oacc[dn] = __builtin_amdgcn_mfma_f32_16x16x32_bf16(pfr[kf], vf, oacc[dn], 0,0,0);
        }
      }
    }
    __builtin_amdgcn_s_setprio(0);
    __syncthreads();
    if (kt < 15){
      *(i32x4*)(Ksb + kdst) = kreg;
      *(i32x4*)(Vsb + vdst) = vreg;
      __syncthreads();
    }
  }
  float ls = lpart;
  ls += __shfl_xor(ls, 16);
  ls += __shfl_xor(ls, 32);
  float linv[4];
  #pragma unroll
  for (int r=0;r<4;r++)
    linv[r] = 1.0f / __shfl(ls, g*4 + r);
  #pragma unroll
  for (int r=0;r<4;r++){
    int qrow = q0 + g*4 + r;
    #pragma unroll
    for (int dn=0;dn<4;dn++)
      ctx[((size_t)(b*2048 + qrow))*512 + h*64 + dn*16 + lrow] = f2bf(oacc[dn][r] * linv[r]);
  }
}

__global__ void k_scan(const int* __restrict__ counts, int* __restrict__ base, int* __restrict__ cur){
  if (threadIdx.x==0 && blockIdx.x==0){
    int s=0;
    for (int e=0;e<8;e++){ base[e]=s; cur[e]=s; s+=counts[e]; }
  }
}

__global__ __launch_bounds__(256) void k_assign(const int* __restrict__ topi,
    int* __restrict__ cur, int* __restrict__ rowof, int* __restrict__ tokof)
{
  __shared__ int lcnt[8];
  __shared__ int gbase[8];
  int tid = threadIdx.x;
  if (tid < 8) lcnt[tid] = 0;
  __syncthreads();
  int t = blockIdx.x*256 + tid;
  int e0 = topi[t*2], e1 = topi[t*2+1];
  int r0 = atomicAdd(&lcnt[e0], 1);
  int r1 = atomicAdd(&lcnt[e1], 1);
  __syncthreads();
  if (tid < 8) gbase[tid] = atomicAdd(&cur[tid], lcnt[tid]);
  __syncthreads();
  int row0 = gbase[e0] + r0, row1 = gbase[e1] + r1;
  rowof[t*2]   = row0;  rowof[t*2+1] = row1;
  tokof[row0] = t;      tokof[row1] = t;
}

// combine: out = x1(fp32) + w0*y0 + w1*y1 ; one float4 per thread
__global__ __launch_bounds__(256) void k_combine(const float* __restrict__ x1, const u16* __restrict__ y,
    const int* __restrict__ rowof, const float* __restrict__ topw, float* __restrict__ out)
{
  int idx = blockIdx.x*256 + threadIdx.x;
  int t = idx >> 7, dq = idx & 127;
  int r0 = rowof[t*2], r1 = rowof[t*2+1];
  float w0 = topw[t*2], w1 = topw[t*2+1];
  size_t o = (size_t)t*512 + dq*4;
  float4 x = *(const float4*)(x1 + o);
  bf16x4 y0 = *(const bf16x4*)(y + (size_t)r0*512 + dq*4);
  bf16x4 y1 = *(const bf16x4*)(y + (size_t)r1*512 + dq*4);
  float4 r;
  r.x = x.x + w0*bf2f((u16)y0[0]) + w1*bf2f((u16)y1[0]);
  r.y = x.y + w0*bf2f((u16)y0[1]) + w1*bf2f((u16)y1[1]);
  r.z = x.z + w0*bf2f((u16)y0[2]) + w1*bf2f((u16)y1[2]);
  r.w = x.w + w0*bf2f((u16)y0[3]) + w1*bf2f((u16)y1[3]);
  *(float4*)(out + o) = r;
}

extern "C" void kernel_launch(void* const* d_in, const int* in_sizes, int n_in,
                              void* d_out, int out_size, void* d_ws, size_t ws_size,
                              hipStream_t stream)
{
  const float* inputs = (const float*)d_in[0];
  const float* rms1_w = (const float*)d_in[1];
  const float* wq  = (const float*)d_in[2];
  const float* bq  = (const float*)d_in[3];
  const float* wk  = (const float*)d_in[4];
  const float* bk  = (const float*)d_in[5];
  const float* wv  = (const float*)d_in[6];
  const float* bv  = (const float*)d_in[7];
  const float* wo  = (const float*)d_in[8];
  const float* bo  = (const float*)d_in[9];
  const float* rms2_w = (const float*)d_in[10];
  const float* gate_w = (const float*)d_in[11];
  const float* ew1 = (const float*)d_in[12];
  const float* eb1 = (const float*)d_in[13];
  const float* ew2 = (const float*)d_in[14];
  const float* eb2 = (const float*)d_in[15];
  char* ws = (char*)d_ws;

  size_t off = 0;
  u16* WQKV = (u16*)(ws + off); off += 1536ull*512*2;
  u16* WOT  = (u16*)(ws + off); off += 512ull*512*2;
  u16* E1T  = (u16*)(ws + off); off += 8ull*1024*512*2;
  u16* E2T  = (u16*)(ws + off); off += 8ull*512*1024*2;
  u16* XN   = (u16*)(ws + off); u16* Hbuf = XN;      off += 8192ull*512*2;   // H aliases XN
  u16* Qb   = (u16*)(ws + off); off += 4ull*8*2048*64*2;
  u16* Kb   = (u16*)(ws + off); off += 4ull*8*2048*64*2;
  u16* Vb   = (u16*)(ws + off); off += 4ull*8*2048*64*2;
  u16* CTX  = (u16*)(ws + off); u16* Yb = CTX;       off += 8192ull*512*2;   // Y aliases CTX
  float* XN2F = (float*)(ws + off); u16* VbT = (u16*)XN2F; off += 8192ull*512*4;  // VbT aliases
  float* X1   = (float*)(ws + off); off += 8192ull*512*4;
  u16* XN2B   = (u16*)(ws + off); off += 8192ull*512*2;
  int*   TOPI = (int*)(ws + off); off += 16384*4;
  float* TOPW = (float*)(ws + off); off += 16384*4;
  int*  ROWOF = (int*)(ws + off); off += 16384*4;
  int*  TOKOF = (int*)(ws + off); off += 16384*4;
  int*  CNT   = (int*)(ws + off); off += 64;
  int*  BASE  = (int*)(ws + off); off += 64;
  int*  CUR   = (int*)(ws + off); off += 64;
  if (ws_size < off) return;
  (void)XN2F;

  // weight conversion: 4x 512x512 in one launch; experts separately
  k_tconv4<<<dim3(8,8,4),  256, 0, stream>>>(wq, wk, wv, wo, WQKV);   // WOT contiguous after WQKV
  k_tconv<<<dim3(16,8,8),  256, 0, stream>>>(ew1, E1T,  512, 1024);
  k_tconv<<<dim3(8,16,8),  256, 0, stream>>>(ew2, E2T, 1024,  512);

  // rmsnorm1 -> xn (bf16)
  k_rmsnorm<<<8192, 256, 0, stream>>>(inputs, rms1_w, XN);

  // QKV projection (Q pre-scaled by 0.125*log2e)
  k_gemm<0><<<64*12, 256, 0, stream>>>(XN, WQKV, 1536, 512, bq, bk, bv,
      nullptr, nullptr, Qb, Kb, Vb, nullptr, nullptr, nullptr);

  // V transpose: [bh][s][d] -> [bh][d][s]
  k_vtrans<<<dim3(32,32), 256, 0, stream>>>(Vb, VbT);

  // attention -> ctx [T,512] bf16  (QBLK=256, 16 waves, 1 block/CU)
  k_attn<<<256, 1024, 0, stream>>>(Qb, Kb, VbT, CTX);

  // output projection + residual -> x1 fp32
  k_gemm<1><<<64*4, 256, 0, stream>>>(CTX, WOT, 512, 512, bo, nullptr, nullptr,
      inputs, X1, nullptr, nullptr, nullptr, nullptr, nullptr, nullptr);

  // fused rmsnorm2 + gate -> xn2 bf16, top-2 (fp32 input)
  k_rmsgate<<<8192, 256, 0, stream>>>(X1, rms2_w, gate_w, XN2B, TOPI, TOPW);

  // routing
  hipMemsetAsync(CNT, 0, 192, stream);
  k_count<<<64, 256, 0, stream>>>(TOPI, CNT);
  k_scan<<<1, 64, 0, stream>>>(CNT, BASE, CUR);
  k_assign<<<32, 256, 0, stream>>>(TOPI, CUR, ROWOF, TOKOF);

  // MoE expert GEMMs (expert = bid&7 -> XCD-pinned experts)
  k_gemm<2><<<8*128*8, 256, 0, stream>>>(XN2B, E1T, 1024, 512, eb1, nullptr, nullptr,
      nullptr, nullptr, Hbuf, nullptr, nullptr, BASE, CNT, TOKOF);
  k_gemm<3><<<8*128*4, 256, 0, stream>>>(Hbuf, E2T, 512, 1024, eb2, nullptr, nullptr,
      nullptr, nullptr, Yb, nullptr, nullptr, BASE, CNT, TOKOF);

  // combine: out = x1 + w0*y0 + w1*y1
  k_combine<<<4096, 256, 0, stream>>>(X1, Yb, ROWOF, TOPW, (float*)d_out);
}

// Round 17
// 222.706 us; speedup vs baseline: 1.0036x; 1.0036x over previous
//
#include <hip/hip_runtime.h>
#include <hip/hip_bf16.h>

typedef unsigned short u16;
typedef __attribute__((ext_vector_type(8))) short short8;   // 8 bf16
typedef __attribute__((ext_vector_type(4))) short bf16x4;   // 4 bf16
typedef __attribute__((ext_vector_type(4))) float f32x4;
typedef __attribute__((ext_vector_type(4))) int i32x4;
typedef __attribute__((ext_vector_type(2))) unsigned u32x2;

#define DEV __device__ __forceinline__

DEV float bf2f(u16 v){ unsigned u = ((unsigned)v)<<16; float f; __builtin_memcpy(&f,&u,4); return f; }
DEV u16 f2bf(float f){ unsigned u; __builtin_memcpy(&u,&f,4); u += 0x7fff + ((u>>16)&1); return (u16)(u>>16); }

// async 16B global -> LDS (wave-uniform LDS base + lane*16; per-lane global addr)
DEV void gload16(const void* g, void* l){
  __builtin_amdgcn_global_load_lds((const __attribute__((address_space(1))) void*)g,
                                   (__attribute__((address_space(3))) void*)l, 16, 0, 0);
}

// pack two f32 -> one u32 of 2 bf16 via compiler-managed cvt_pk
DEV unsigned packbf2(float a, float b){
  float2 f = {a, b};
  __hip_bfloat162 h = __float22bfloat162_rn(f);
  unsigned w; __builtin_memcpy(&w, &h, 4);
  return w;
}

// dims: B=4 S=2048 D=512 H=8 HD=64 E=8 K=2 F=1024, T=8192

// ---------------- coalesced transpose+convert: src fp32 [R][C] -> dst bf16 [C][R], z selects matrix ----------------
__global__ __launch_bounds__(256) void k_tconv4(const float* __restrict__ s0, const float* __restrict__ s1,
    const float* __restrict__ s2, const float* __restrict__ s3, u16* __restrict__ dst){
  int z = blockIdx.z;
  const float* src = z==0 ? s0 : (z==1 ? s1 : (z==2 ? s2 : s3));
  dst += (size_t)z * 512 * 512;
  int r0 = blockIdx.y * 64, c0 = blockIdx.x * 64;
  __shared__ u16 tile[64][68];
  int tid = threadIdx.x;
  int rr = tid >> 4, cc = (tid & 15) * 4;
  #pragma unroll
  for (int it = 0; it < 4; ++it){
    int r = it*16 + rr;
    float4 v = *(const float4*)(src + (size_t)(r0 + r)*512 + c0 + cc);
    bf16x4 pk = { (short)f2bf(v.x), (short)f2bf(v.y), (short)f2bf(v.z), (short)f2bf(v.w) };
    *(bf16x4*)&tile[r][cc] = pk;
  }
  __syncthreads();
  #pragma unroll
  for (int it = 0; it < 4; ++it){
    int c = it*16 + rr;
    bf16x4 pk = { (short)tile[cc+0][c], (short)tile[cc+1][c],
                  (short)tile[cc+2][c], (short)tile[cc+3][c] };
    *(bf16x4*)(dst + (size_t)(c0 + c)*512 + r0 + cc) = pk;
  }
}

__global__ __launch_bounds__(256) void k_tconv(const float* __restrict__ src, u16* __restrict__ dst,
    int R, int C){
  src += (size_t)blockIdx.z * R * C;
  dst += (size_t)blockIdx.z * R * C;
  int r0 = blockIdx.y * 64, c0 = blockIdx.x * 64;
  __shared__ u16 tile[64][68];
  int tid = threadIdx.x;
  int rr = tid >> 4, cc = (tid & 15) * 4;
  #pragma unroll
  for (int it = 0; it < 4; ++it){
    int r = it*16 + rr;
    float4 v = *(const float4*)(src + (size_t)(r0 + r)*C + c0 + cc);
    bf16x4 pk = { (short)f2bf(v.x), (short)f2bf(v.y), (short)f2bf(v.z), (short)f2bf(v.w) };
    *(bf16x4*)&tile[r][cc] = pk;
  }
  __syncthreads();
  #pragma unroll
  for (int it = 0; it < 4; ++it){
    int c = it*16 + rr;
    bf16x4 pk = { (short)tile[cc+0][c], (short)tile[cc+1][c],
                  (short)tile[cc+2][c], (short)tile[cc+3][c] };
    *(bf16x4*)(dst + (size_t)(c0 + c)*R + r0 + cc) = pk;
  }
}

// ---------------- bf16 transpose per head: [2048 s][64 d] -> [64 d][2048 s] ----------------
__global__ __launch_bounds__(256) void k_vtrans(const u16* __restrict__ src, u16* __restrict__ dst){
  int bh = blockIdx.y; int s0 = blockIdx.x*64;
  src += (size_t)bh*2048*64 + (size_t)s0*64;
  dst += (size_t)bh*64*2048 + s0;
  __shared__ unsigned tile[64*33];
  int tid = threadIdx.x;
  #pragma unroll
  for (int it = 0; it < 2; ++it){
    int c = tid + it*256;
    int r = c >> 3, c8 = c & 7;
    i32x4 v = *(const i32x4*)(src + (size_t)r*64 + c8*8);
    *(i32x4*)&tile[r*33 + c8*4] = v;
  }
  __syncthreads();
  #pragma unroll
  for (int it = 0; it < 2; ++it){
    int c = tid + it*256;
    int d = c >> 3, s8 = c & 7;
    union { i32x4 v; u16 us[8]; } o;
    #pragma unroll
    for (int j = 0; j < 8; ++j){
      unsigned w = tile[(s8*8+j)*33 + (d>>1)];
      o.us[j] = (d & 1) ? (u16)(w >> 16) : (u16)(w & 0xffff);
    }
    *(i32x4*)(dst + (size_t)d*2048 + s8*8) = o.v;
  }
}

// ---------------- RMSNorm1 ----------------
__global__ __launch_bounds__(256) void k_rmsnorm(const float* __restrict__ x, const float* __restrict__ w,
    u16* __restrict__ ob){
  int t = blockIdx.x, tid = threadIdx.x;
  const float* xr = x + (size_t)t*512;
  float2 v = *(const float2*)(xr + tid*2);
  float ss = v.x*v.x + v.y*v.y;
  #pragma unroll
  for (int o=32; o>0; o>>=1) ss += __shfl_down(ss, o);
  __shared__ float sred[4];
  if ((tid&63)==0) sred[tid>>6] = ss;
  __syncthreads();
  float tot = sred[0]+sred[1]+sred[2]+sred[3];
  float inv = rsqrtf(tot*(1.f/512.f) + 1e-6f);
  float2 wv = *(const float2*)(w + tid*2);
  ob[(size_t)t*512 + tid*2]     = f2bf(v.x*inv*wv.x);
  ob[(size_t)t*512 + tid*2 + 1] = f2bf(v.y*inv*wv.y);
}

// ---------------- fused RMSNorm2 + gate logits + top-2 (fp32 X1 — routing must match fp32 reference) ----------------
__global__ __launch_bounds__(256) void k_rmsgate(const float* __restrict__ x, const float* __restrict__ w,
    const float* __restrict__ gw, u16* __restrict__ ob, int* __restrict__ topi, float* __restrict__ topw){
  int t = blockIdx.x, tid = threadIdx.x;
  const float* xr = x + (size_t)t*512;
  float2 v = *(const float2*)(xr + tid*2);
  float ss = v.x*v.x + v.y*v.y;
  #pragma unroll
  for (int o=32; o>0; o>>=1) ss += __shfl_down(ss, o);
  __shared__ float sred[4];
  if ((tid&63)==0) sred[tid>>6] = ss;
  __syncthreads();
  float tot = sred[0]+sred[1]+sred[2]+sred[3];
  float inv = rsqrtf(tot*(1.f/512.f) + 1e-6f);
  float2 wv = *(const float2*)(w + tid*2);
  float y0 = v.x*inv*wv.x, y1 = v.y*inv*wv.y;
  ob[(size_t)t*512 + tid*2]     = f2bf(y0);
  ob[(size_t)t*512 + tid*2 + 1] = f2bf(y1);
  float acc[8];
  const float* g0 = gw + tid*16;
  #pragma unroll
  for (int e=0;e<8;e++) acc[e] = y0*g0[e] + y1*g0[8+e];
  #pragma unroll
  for (int dd=1; dd<64; dd<<=1)
    #pragma unroll
    for (int e=0;e<8;e++) acc[e] += __shfl_xor(acc[e], dd);
  __shared__ float gred[4][8];
  if ((tid&63)==0)
    #pragma unroll
    for (int e=0;e<8;e++) gred[tid>>6][e] = acc[e];
  __syncthreads();
  if (tid==0){
    float l[8];
    #pragma unroll
    for (int e=0;e<8;e++) l[e] = gred[0][e]+gred[1][e]+gred[2][e]+gred[3][e];
    int i0=0; float a0=l[0];
    #pragma unroll
    for (int e=1;e<8;e++) if (l[e]>a0){ a0=l[e]; i0=e; }
    int i1=-1; float a1=-1e30f;
    #pragma unroll
    for (int e=0;e<8;e++) if (e!=i0 && l[e]>a1){ a1=l[e]; i1=e; }
    float w1 = __expf(a1 - a0);
    float invs = 1.f / (1.f + w1);
    topi[t*2]=i0; topi[t*2+1]=i1;
    topw[t*2]=invs; topw[t*2+1]=w1*invs;
  }
}

// ---------------- expert histogram ----------------
__global__ __launch_bounds__(256) void k_count(const int* __restrict__ topi, int* __restrict__ counts){
  __shared__ int lcnt[8];
  if (threadIdx.x < 8) lcnt[threadIdx.x] = 0;
  __syncthreads();
  for (int i = blockIdx.x*256 + threadIdx.x; i < 16384; i += 256*64)
    atomicAdd(&lcnt[topi[i]], 1);
  __syncthreads();
  if (threadIdx.x < 8) atomicAdd(&counts[threadIdx.x], lcnt[threadIdx.x]);
}

// ---------------- TN bf16 GEMM, global_load_lds + double-buffered; XCD-pinned experts ----------------
template<int MODE>
__global__ __launch_bounds__(256) void k_gemm(const u16* __restrict__ A, const u16* __restrict__ Bt,
    int Nsize, int Ksize,
    const float* __restrict__ b0, const float* __restrict__ b1, const float* __restrict__ b2,
    const float* __restrict__ resid, float* __restrict__ outf,
    u16* __restrict__ o0, u16* __restrict__ o1, u16* __restrict__ o2,
    const int* __restrict__ ebase, const int* __restrict__ ecnt, const int* __restrict__ etok)
{
  int nNT = Nsize >> 7;
  int e=0, mt, nt, myBase=0, myCnt=0;
  if constexpr (MODE>=2){
    e = blockIdx.x & 7;
    int rr = blockIdx.x >> 3;
    mt = rr / nNT; nt = rr - mt*nNT;
    myCnt = ecnt[e]; myBase = ebase[e];
    if (mt*128 >= myCnt) return;
    Bt += (size_t)e * Nsize * Ksize;
  } else {
    int q = gridDim.x >> 3;
    int bid = blockIdx.x;
    int swb = (bid & 7)*q + (bid >> 3);
    mt = swb / nNT; nt = swb - mt*nNT;
  }
  __shared__ u16 As[2][128*32];
  __shared__ u16 Bs[2][128*32];
  int tid = threadIdx.x;
  int lane = tid & 63, wid = tid >> 6;
  int wr = (wid>>1)<<6, wc = (wid&1)<<6;
  int lrow = lane & 15, lk8 = (lane>>4)<<3;
  const u16* asrc[2]; const u16* bsrc[2];
  int ldoff[2];
  #pragma unroll
  for (int it=0; it<2; ++it){
    int c = it*256 + tid;
    int r = c >> 2, c4 = c & 3;
    int grow;
    if constexpr (MODE==2){
      int ml = mt*128 + r; if (ml >= myCnt) ml = myCnt-1;
      grow = etok[myBase + ml];
    } else if constexpr (MODE==3){
      int ml = mt*128 + r; if (ml >= myCnt) ml = myCnt-1;
      grow = myBase + ml;
    } else {
      grow = mt*128 + r;
    }
    asrc[it] = A + (size_t)grow*Ksize + c4*8;
    bsrc[it] = Bt + (size_t)(nt*128 + r)*Ksize + c4*8;
    ldoff[it] = (it*256 + wid*64)*8;
  }
  f32x4 acc[4][4] = {};
  int nK = Ksize >> 5;
  #pragma unroll
  for (int it=0; it<2; ++it){
    gload16(asrc[it], &As[0][ldoff[it]]);
    gload16(bsrc[it], &Bs[0][ldoff[it]]);
  }
  __syncthreads();
  for (int ks = 0; ks < nK; ++ks){
    int cur = ks & 1;
    if (ks+1 < nK){
      int k0 = (ks+1) << 5;
      #pragma unroll
      for (int it=0; it<2; ++it){
        gload16(asrc[it] + k0, &As[cur^1][ldoff[it]]);
        gload16(bsrc[it] + k0, &Bs[cur^1][ldoff[it]]);
      }
    }
    short8 a[4], b[4];
    #pragma unroll
    for (int i=0;i<4;i++) a[i] = *(const short8*)(&As[cur][(wr + i*16 + lrow)*32 + lk8]);
    #pragma unroll
    for (int j=0;j<4;j++) b[j] = *(const short8*)(&Bs[cur][(wc + j*16 + lrow)*32 + lk8]);
    #pragma unroll
    for (int i=0;i<4;i++)
      #pragma unroll
      for (int j=0;j<4;j++)
        acc[i][j] = __builtin_amdgcn_mfma_f32_16x16x32_bf16(a[i], b[j], acc[i][j], 0,0,0);
    __syncthreads();
  }
  #pragma unroll
  for (int i=0;i<4;i++){
    #pragma unroll
    for (int r=0;r<4;r++){
      int rowl = mt*128 + wr + i*16 + ((lane>>4)<<2) + r;
      #pragma unroll
      for (int j=0;j<4;j++){
        int col = nt*128 + wc + j*16 + lrow;
        float v = acc[i][j][r];
        if constexpr (MODE==0){
          int which = col >> 9; int hc = col & 511;
          const float* bias = which==0 ? b0 : (which==1 ? b1 : b2);
          v += bias[hc];
          if (which == 0) v *= 0.18033688011112042f;   // fold 0.125*log2(e) into Q
          u16* dst = which==0 ? o0 : (which==1 ? o1 : o2);
          int bidx = rowl >> 11, s = rowl & 2047;
          int h = hc >> 6, hd = hc & 63;
          dst[((size_t)(bidx*8+h)*2048 + s)*64 + hd] = f2bf(v);
        } else if constexpr (MODE==1){
          v += b0[col] + resid[(size_t)rowl*512 + col];
          outf[(size_t)rowl*512 + col] = v;          // X1 fp32 (routing correctness)
        } else if constexpr (MODE==2){
          if (rowl < myCnt){
            v += b0[e*1024 + col];
            v = fmaxf(v, 0.f);
            o0[(size_t)(myBase+rowl)*1024 + col] = f2bf(v);
          }
        } else {
          if (rowl < myCnt){
            v += b0[e*512 + col];
            o0[(size_t)(myBase+rowl)*512 + col] = f2bf(v);
          }
        }
      }
    }
  }
}

// ---------------- flash attention v8: QBLK=256, 16 waves, double-buffered K/V (96KB LDS), 1 barrier/kt ----
__global__ __launch_bounds__(1024) void k_attn(const u16* __restrict__ qb, const u16* __restrict__ kb,
    const u16* __restrict__ vtb, u16* __restrict__ ctx)
{
  int bh = blockIdx.x & 31;        // XCD = bh % 8
  int qt = blockIdx.x >> 5;        // 8 q-tiles of 256
  int b = bh >> 3, h = bh & 7;
  const size_t bho = (size_t)bh * (2048*64);
  int tid = threadIdx.x, lane = tid & 63, wid = tid >> 6;   // 16 waves
  int lrow = lane & 15, g = lane >> 4;
  __shared__ u16 Ks[2][128*64];    // 2x16KB [key][d] rows 128B, XOR-swizzled
  __shared__ u16 Vts[2][64*128];   // 2x16KB [d][key] rows 256B, XOR-swizzled
  __shared__ u16 Ps[16][16*64];    // 32KB per-wave P [q][key-half] rows 128B, XOR-swizzled
  char* Ksb = (char*)&Ks[0][0];
  char* Vsb = (char*)&Vts[0][0];
  char* Psb = (char*)&Ps[wid][0];
  int q0 = qt*256 + wid*16;
  short8 qf[2];
  #pragma unroll
  for (int kf=0;kf<2;kf++)
    qf[kf] = *(const short8*)(qb + bho + (size_t)(q0 + lrow)*64 + kf*32 + g*8);
  f32x4 oacc[4] = {};
  float lpart = 0.f;
  const int swz = (lrow & 7) << 4;

  // staging: K 128x64 and V^T 64x128 = 1024 x 16B chunks each; 1024 threads -> 1 chunk each
  int c = tid;
  int kr = c >> 3, kc8 = c & 7;
  size_t ksrc = bho + (size_t)kr*64 + kc8*8;
  int kdst = kr*128 + ((kc8*16) ^ ((kr&7)<<4));
  int vr = c >> 4, vc16 = c & 15;
  size_t vsrc = bho + (size_t)vr*2048 + vc16*8;
  int vdst = vr*256 + ((vc16*16) ^ ((vr&7)<<4));

  // prologue: tile 0 -> buf 0
  i32x4 kreg = *(const i32x4*)(kb + ksrc);
  i32x4 vreg = *(const i32x4*)(vtb + vsrc);
  *(i32x4*)(Ksb + kdst) = kreg;
  *(i32x4*)(Vsb + vdst) = vreg;
  __syncthreads();

  for (int kt=0; kt<16; ++kt){
    int cb = (kt & 1) * 16384;         // current K/V buffer byte offset
    if (kt < 15){
      int k0 = (kt+1)*128;
      kreg = *(const i32x4*)(kb + ksrc + (size_t)k0*64);
      vreg = *(const i32x4*)(vtb + vsrc + k0);
    }
    __builtin_amdgcn_s_setprio(1);
    #pragma unroll
    for (int hf=0; hf<2; ++hf){
      // QK^T (swapped) + exp for this 64-key half
      #pragma unroll
      for (int nf=0; nf<4; ++nf){
        int krow = hf*64 + nf*16 + lrow;
        short8 kf0 = *(const short8*)(Ksb + cb + krow*128 + ((g*16) ^ swz));
        short8 kf1 = *(const short8*)(Ksb + cb + krow*128 + ((64 + g*16) ^ swz));
        f32x4 s = {};
        s = __builtin_amdgcn_mfma_f32_16x16x32_bf16(kf0, qf[0], s, 0,0,0);
        s = __builtin_amdgcn_mfma_f32_16x16x32_bf16(kf1, qf[1], s, 0,0,0);
        float p0 = __builtin_amdgcn_exp2f(s[0]);
        float p1 = __builtin_amdgcn_exp2f(s[1]);
        float p2 = __builtin_amdgcn_exp2f(s[2]);
        float p3 = __builtin_amdgcn_exp2f(s[3]);
        lpart += (p0+p1)+(p2+p3);
        *(u32x2*)(Psb + lrow*128 + ((nf*32 + g*8) ^ swz)) = (u32x2){packbf2(p0,p1), packbf2(p2,p3)};
      }
      // PV for this half
      short8 pfr[2];
      #pragma unroll
      for (int kf=0;kf<2;kf++)
        pfr[kf] = *(const short8*)(Psb + lrow*128 + ((kf*64 + g*16) ^ swz));
      #pragma unroll
      for (int dn=0;dn<4;dn++){
        #pragma unroll
        for (int kf=0;kf<2;kf++){
          short8 vf = *(const short8*)(Vsb + cb + (dn*16+lrow)*256 + ((hf*128 + kf*64 + g*16) ^ swz));
          oacc[dn] = __builtin_amdgcn_mfma_f32_16x16x32_bf16(pfr[kf], vf, oacc[dn], 0,0,0);
        }
      }
    }
    __builtin_amdgcn_s_setprio(0);
    if (kt < 15){
      int nb = cb ^ 16384;             // next buffer
      *(i32x4*)(Ksb + nb + kdst) = kreg;
      *(i32x4*)(Vsb + nb + vdst) = vreg;
      __syncthreads();                 // single barrier: publishes next buf + releases current
    }
  }
  // denominator: reduce over the 4 g-replicas of each q-column
  float ls = lpart;
  ls += __shfl_xor(ls, 16);
  ls += __shfl_xor(ls, 32);
  float linv[4];
  #pragma unroll
  for (int r=0;r<4;r++)
    linv[r] = 1.0f / __shfl(ls, g*4 + r);
  #pragma unroll
  for (int r=0;r<4;r++){
    int qrow = q0 + g*4 + r;
    #pragma unroll
    for (int dn=0;dn<4;dn++)
      ctx[((size_t)(b*2048 + qrow))*512 + h*64 + dn*16 + lrow] = f2bf(oacc[dn][r] * linv[r]);
  }
}

__global__ void k_scan(const int* __restrict__ counts, int* __restrict__ base, int* __restrict__ cur){
  if (threadIdx.x==0 && blockIdx.x==0){
    int s=0;
    for (int e=0;e<8;e++){ base[e]=s; cur[e]=s; s+=counts[e]; }
  }
}

__global__ __launch_bounds__(256) void k_assign(const int* __restrict__ topi,
    int* __restrict__ cur, int* __restrict__ rowof, int* __restrict__ tokof)
{
  __shared__ int lcnt[8];
  __shared__ int gbase[8];
  int tid = threadIdx.x;
  if (tid < 8) lcnt[tid] = 0;
  __syncthreads();
  int t = blockIdx.x*256 + tid;
  int e0 = topi[t*2], e1 = topi[t*2+1];
  int r0 = atomicAdd(&lcnt[e0], 1);
  int r1 = atomicAdd(&lcnt[e1], 1);
  __syncthreads();
  if (tid < 8) gbase[tid] = atomicAdd(&cur[tid], lcnt[tid]);
  __syncthreads();
  int row0 = gbase[e0] + r0, row1 = gbase[e1] + r1;
  rowof[t*2]   = row0;  rowof[t*2+1] = row1;
  tokof[row0] = t;      tokof[row1] = t;
}

// combine: out = x1(fp32) + w0*y0 + w1*y1 ; one float4 per thread
__global__ __launch_bounds__(256) void k_combine(const float* __restrict__ x1, const u16* __restrict__ y,
    const int* __restrict__ rowof, const float* __restrict__ topw, float* __restrict__ out)
{
  int idx = blockIdx.x*256 + threadIdx.x;
  int t = idx >> 7, dq = idx & 127;
  int r0 = rowof[t*2], r1 = rowof[t*2+1];
  float w0 = topw[t*2], w1 = topw[t*2+1];
  size_t o = (size_t)t*512 + dq*4;
  float4 x = *(const float4*)(x1 + o);
  bf16x4 y0 = *(const bf16x4*)(y + (size_t)r0*512 + dq*4);
  bf16x4 y1 = *(const bf16x4*)(y + (size_t)r1*512 + dq*4);
  float4 r;
  r.x = x.x + w0*bf2f((u16)y0[0]) + w1*bf2f((u16)y1[0]);
  r.y = x.y + w0*bf2f((u16)y0[1]) + w1*bf2f((u16)y1[1]);
  r.z = x.z + w0*bf2f((u16)y0[2]) + w1*bf2f((u16)y1[2]);
  r.w = x.w + w0*bf2f((u16)y0[3]) + w1*bf2f((u16)y1[3]);
  *(float4*)(out + o) = r;
}

extern "C" void kernel_launch(void* const* d_in, const int* in_sizes, int n_in,
                              void* d_out, int out_size, void* d_ws, size_t ws_size,
                              hipStream_t stream)
{
  const float* inputs = (const float*)d_in[0];
  const float* rms1_w = (const float*)d_in[1];
  const float* wq  = (const float*)d_in[2];
  const float* bq  = (const float*)d_in[3];
  const float* wk  = (const float*)d_in[4];
  const float* bk  = (const float*)d_in[5];
  const float* wv  = (const float*)d_in[6];
  const float* bv  = (const float*)d_in[7];
  const float* wo  = (const float*)d_in[8];
  const float* bo  = (const float*)d_in[9];
  const float* rms2_w = (const float*)d_in[10];
  const float* gate_w = (const float*)d_in[11];
  const float* ew1 = (const float*)d_in[12];
  const float* eb1 = (const float*)d_in[13];
  const float* ew2 = (const float*)d_in[14];
  const float* eb2 = (const float*)d_in[15];
  char* ws = (char*)d_ws;

  size_t off = 0;
  u16* WQKV = (u16*)(ws + off); off += 1536ull*512*2;
  u16* WOT  = (u16*)(ws + off); off += 512ull*512*2;
  u16* E1T  = (u16*)(ws + off); off += 8ull*1024*512*2;
  u16* E2T  = (u16*)(ws + off); off += 8ull*512*1024*2;
  u16* XN   = (u16*)(ws + off); u16* Hbuf = XN;      off += 8192ull*512*2;   // H aliases XN
  u16* Qb   = (u16*)(ws + off); off += 4ull*8*2048*64*2;
  u16* Kb   = (u16*)(ws + off); off += 4ull*8*2048*64*2;
  u16* Vb   = (u16*)(ws + off); off += 4ull*8*2048*64*2;
  u16* CTX  = (u16*)(ws + off); u16* Yb = CTX;       off += 8192ull*512*2;   // Y aliases CTX
  float* XN2F = (float*)(ws + off); u16* VbT = (u16*)XN2F; off += 8192ull*512*4;  // VbT aliases
  float* X1   = (float*)(ws + off); off += 8192ull*512*4;
  u16* XN2B   = (u16*)(ws + off); off += 8192ull*512*2;
  int*   TOPI = (int*)(ws + off); off += 16384*4;
  float* TOPW = (float*)(ws + off); off += 16384*4;
  int*  ROWOF = (int*)(ws + off); off += 16384*4;
  int*  TOKOF = (int*)(ws + off); off += 16384*4;
  int*  CNT   = (int*)(ws + off); off += 64;
  int*  BASE  = (int*)(ws + off); off += 64;
  int*  CUR   = (int*)(ws + off); off += 64;
  if (ws_size < off) return;
  (void)XN2F;

  // weight conversion: 4x 512x512 in one launch; experts separately
  k_tconv4<<<dim3(8,8,4),  256, 0, stream>>>(wq, wk, wv, wo, WQKV);   // WOT contiguous after WQKV
  k_tconv<<<dim3(16,8,8),  256, 0, stream>>>(ew1, E1T,  512, 1024);
  k_tconv<<<dim3(8,16,8),  256, 0, stream>>>(ew2, E2T, 1024,  512);

  // rmsnorm1 -> xn (bf16)
  k_rmsnorm<<<8192, 256, 0, stream>>>(inputs, rms1_w, XN);

  // QKV projection (Q pre-scaled by 0.125*log2e)
  k_gemm<0><<<64*12, 256, 0, stream>>>(XN, WQKV, 1536, 512, bq, bk, bv,
      nullptr, nullptr, Qb, Kb, Vb, nullptr, nullptr, nullptr);

  // V transpose: [bh][s][d] -> [bh][d][s]
  k_vtrans<<<dim3(32,32), 256, 0, stream>>>(Vb, VbT);

  // attention -> ctx [T,512] bf16  (QBLK=256, 16 waves, 1 block/CU, double-buffered K/V)
  k_attn<<<256, 1024, 0, stream>>>(Qb, Kb, VbT, CTX);

  // output projection + residual -> x1 fp32
  k_gemm<1><<<64*4, 256, 0, stream>>>(CTX, WOT, 512, 512, bo, nullptr, nullptr,
      inputs, X1, nullptr, nullptr, nullptr, nullptr, nullptr, nullptr);

  // fused rmsnorm2 + gate -> xn2 bf16, top-2 (fp32 input)
  k_rmsgate<<<8192, 256, 0, stream>>>(X1, rms2_w, gate_w, XN2B, TOPI, TOPW);

  // routing
  hipMemsetAsync(CNT, 0, 192, stream);
  k_count<<<64, 256, 0, stream>>>(TOPI, CNT);
  k_scan<<<1, 64, 0, stream>>>(CNT, BASE, CUR);
  k_assign<<<32, 256, 0, stream>>>(TOPI, CUR, ROWOF, TOKOF);

  // MoE expert GEMMs (expert = bid&7 -> XCD-pinned; 64 M-tiles/expert covers 8192 rows, counts ~2048)
  k_gemm<2><<<8*64*8, 256, 0, stream>>>(XN2B, E1T, 1024, 512, eb1, nullptr, nullptr,
      nullptr, nullptr, Hbuf, nullptr, nullptr, BASE, CNT, TOKOF);
  k_gemm<3><<<8*64*4, 256, 0, stream>>>(Hbuf, E2T, 512, 1024, eb2, nullptr, nullptr,
      nullptr, nullptr, Yb, nullptr, nullptr, BASE, CNT, TOKOF);

  // combine: out = x1 + w0*y0 + w1*y1
  k_combine<<<4096, 256, 0, stream>>>(X1, Yb, ROWOF, TOPW, (float*)d_out);
}